// Round 10
// baseline (307.563 us; speedup 1.0000x reference)
//
#include <hip/hip_runtime.h>
#include <math.h>

// Shapes (fixed by the reference)
#define DXc   16
#define MRc   64
#define MBARc 256
#define NTc   9
#define DYc   8
#define HXc   1024
#define EXc   512
#define HRc   512
#define HBc   2048
#define GOUTc 64
#define TOTc  2049   // (NT-1)*MBAR + 1

using bf16x8 = __attribute__((ext_vector_type(8))) short;
using f32x4  = __attribute__((ext_vector_type(4))) float;

typedef unsigned int u32;
typedef u32 __attribute__((address_space(1))) gbl_u32;
typedef u32 __attribute__((address_space(3))) lds_u32;

__device__ __forceinline__ float fast_tanh(float x){
    float e = __expf(2.0f * x);
    return 1.0f - 2.0f / (e + 1.0f);
}

// fp32 -> bf16 round-to-nearest-even (bit pattern in a short)
__device__ __forceinline__ short f2bf(float f){
    unsigned u = __builtin_bit_cast(unsigned, f);
    u = (u + 0x7FFFu + ((u >> 16) & 1u)) >> 16;
    return (short)u;
}

// async global->LDS: each lane loads 16 B from g + lane*16; LDS dest = base + lane*16
__device__ __forceinline__ void gld_lds16(const short* g, short* l){
    __builtin_amdgcn_global_load_lds((const gbl_u32*)g, (lds_u32*)l, 16, 0, 0);
}

// ---------------- prep: SW + packs (Wx2a A-layout, Wb1p B-layout) + XW/T1 + wrow + inits ----------------
// grid 4673 x 256
__global__ void prep_kernel(const float* __restrict__ stoich, const float* __restrict__ Wx1,
                            const float* __restrict__ Wx2, const float* __restrict__ Wb1,
                            const float* __restrict__ X, const float* __restrict__ R,
                            const float* __restrict__ bx1, const float* __restrict__ bx2,
                            const int* kpptr, const int* qpptr,
                            float* __restrict__ SW, short* __restrict__ Wx2a,
                            short* __restrict__ Wb1p, float* __restrict__ XW,
                            float* __restrict__ T1, float* __restrict__ wrow,
                            float* __restrict__ hb0, float* __restrict__ dacc,
                            float* __restrict__ outz, float* __restrict__ eXb,
                            float* __restrict__ Z2Bacc){
    int b = blockIdx.x, tid = threadIdx.x;
    if (b < 256){
        // SW[j][c] = stoich[:,j] @ Wx1
        int idx = b * 256 + tid;
        int j = idx >> 10, c = idx & 1023;
        float acc = 0.f;
        #pragma unroll
        for (int d = 0; d < DXc; ++d) acc += stoich[d * MRc + j] * Wx1[d * HXc + c];
        SW[idx] = acc;
    } else if (b < 512){
        // pack Wx2 (1024x512) into MFMA A-fragment order (M=c rows, K=e), KTOT=16
        size_t grp = (size_t)(b - 256) * 256 + tid;    // 65536 groups
        int lane = grp & 63;
        size_t t2 = grp >> 6;
        int kt = t2 & 15, mt = t2 >> 4;                // mt 0..63
        int c  = mt * 16 + (lane & 15);
        int e0 = kt * 32 + ((lane >> 4) << 3);
        short o8[8];
        #pragma unroll
        for (int jj = 0; jj < 8; ++jj) o8[jj] = f2bf(Wx2[(size_t)c * EXc + e0 + jj]);
        *(bf16x8*)(Wx2a + grp * 8) = *(bf16x8*)o8;
    } else if (b < 1024){
        // pack Wb1 rows 1..512 (512x2048) into B-fragment order, KTOT=16
        size_t grp = (size_t)(b - 512) * 256 + tid;
        int lane = grp & 63;
        size_t t2 = grp >> 6;
        int kt = t2 & 15, nt = t2 >> 4;
        int n  = nt * 16 + (lane & 15);
        int k0 = kt * 32 + ((lane >> 4) << 3);
        short o8[8];
        #pragma unroll
        for (int jj = 0; jj < 8; ++jj) o8[jj] = f2bf(Wb1[(size_t)(1 + k0 + jj) * HBc + n]);
        *(bf16x8*)(Wb1p + grp * 8) = *(bf16x8*)o8;
    } else if (b < 2048){
        // XW = Xbase@Wx1 + bx1 ; T1 = tanh(XW)
        int idx = (b - 1024) * 256 + tid;
        int m = idx >> 10, c = idx & 1023;
        int base = kpptr[0] * MBARc;
        const float* xr = X + ((size_t)qpptr[0] * TOTc + base + m) * DXc;
        float acc = bx1[c];
        #pragma unroll
        for (int d = 0; d < DXc; ++d) acc += xr[d] * Wx1[d * HXc + c];
        XW[idx] = acc;
        T1[idx] = fast_tanh(acc);
    } else if (b < 2112){
        // wrow[j*256+m] = valid(j,m) * R_delta
        int j = b - 2048, m = tid;
        int base = kpptr[0] * MBARc;
        int qp = qpptr[0];
        const float* xr = X + ((size_t)qp * TOTc + base + m) * DXc;
        bool valid = true;
        #pragma unroll
        for (int d = 0; d < DXc; ++d) valid = valid && (xr[d] + stoich[d * MRc + j] >= 0.f);
        size_t rb = (size_t)qp * TOTc * MRc;
        float rd = R[rb + (size_t)(base + 1 + m) * MRc + j] - R[rb + (size_t)(base + m) * MRc + j];
        wrow[j * MBARc + m] = valid ? rd : 0.f;
    } else if (b == 2112){
        hb0[tid] = 0.f; hb0[tid + 256] = 0.f;
        #pragma unroll
        for (int l = 0; l < 8; ++l) dacc[tid + l * 256] = 0.f;
        if (tid < GOUTc) outz[tid] = 0.f;
    } else if (b < 2625){
        // eXb init = bx2 (broadcast per row); 512 blocks, 131072 elems
        int idx = (b - 2113) * 256 + tid;
        eXb[idx] = bx2[idx & 511];
    } else {
        // Z2Bacc = 0; 2048 blocks, 524288 elems
        Z2Bacc[(size_t)(b - 2625) * 256 + tid] = 0.f;
    }
}

// ---------------- RNN step: h_next = tanh(y_t@Wih + h_cur@Whh + bh) ----------------
__global__ __launch_bounds__(512) void rnn_step_kernel(
    const float* __restrict__ Y, const float* __restrict__ Wih,
    const float* __restrict__ Whh, const float* __restrict__ bh,
    const int* kptr, const int* qptr,
    const float* __restrict__ h_cur, float* __restrict__ h_next, int step){
    __shared__ float hs[HRc];
    __shared__ float psum[8][64];
    int tid = threadIdx.x;
    int o   = tid & 63;
    int seg = tid >> 6;
    int out = blockIdx.x * 64 + o;
    int k = kptr[0], q = qptr[0];
    int t = k + 1 + step;
    hs[tid] = h_cur[tid];
    __syncthreads();
    if (t >= NTc){
        if (seg == 0) h_next[out] = hs[out];
        return;
    }
    int k0 = seg * 64;
    float a0 = 0.f, a1 = 0.f, a2 = 0.f, a3 = 0.f;
    #pragma unroll 4
    for (int kk = 0; kk < 64; kk += 4){
        a0 += hs[k0 + kk + 0] * Whh[(size_t)(k0 + kk + 0) * HRc + out];
        a1 += hs[k0 + kk + 1] * Whh[(size_t)(k0 + kk + 1) * HRc + out];
        a2 += hs[k0 + kk + 2] * Whh[(size_t)(k0 + kk + 2) * HRc + out];
        a3 += hs[k0 + kk + 3] * Whh[(size_t)(k0 + kk + 3) * HRc + out];
    }
    psum[seg][o] = (a0 + a1) + (a2 + a3);
    __syncthreads();
    if (seg == 0){
        float a = 0.f;
        #pragma unroll
        for (int r = 0; r < 8; ++r) a += psum[r][o];
        const float* y = Y + (q * NTc + t) * DYc;
        float z = bh[out];
        #pragma unroll
        for (int d = 0; d < DYc; ++d) z += y[d] * Wih[d * HRc + out];
        h_next[out] = fast_tanh(z + a);
    }
}

// ---------------- cY[h] = bb1[h] + eY @ Wb1[513:1025], split-K in-block ----------------
__global__ __launch_bounds__(256) void cy_kernel(const float* __restrict__ eY,
                                                 const float* __restrict__ Wb1,
                                                 const float* __restrict__ bb1,
                                                 float* __restrict__ cY){
    __shared__ float psum[4][64];
    int tid = threadIdx.x;
    int o = tid & 63, seg = tid >> 6;
    int h = blockIdx.x * 64 + o;
    int e0 = seg * 128;
    float acc = 0.f;
    #pragma unroll 4
    for (int e = 0; e < 128; ++e)
        acc += eY[e0 + e] * Wb1[(size_t)(1 + EXc + e0 + e) * HBc + h];
    psum[seg][o] = acc;
    __syncthreads();
    if (seg == 0)
        cY[h] = bb1[h] + psum[0][o] + psum[1][o] + psum[2][o] + psum[3][o];
}

// ---------------- exbase split-K: eXb += T1 @ Wx2 (eXb pre-init to bx2) ----------------
__global__ __launch_bounds__(256) void exbase_kernel(const float* __restrict__ T1,
                                                     const float* __restrict__ Wx2,
                                                     float* __restrict__ eXb){
    __shared__ float t1s[8 * 128];
    int b = blockIdx.x, tid = threadIdx.x;
    int mg = b & 31, eh = (b >> 5) & 1, kq = b >> 6;
    int m0 = mg * 8, e = eh * 256 + tid, k0 = kq * 128;
    #pragma unroll
    for (int l = 0; l < 4; ++l){
        int idx = tid + l * 256;
        t1s[idx] = T1[(size_t)(m0 + (idx >> 7)) * HXc + k0 + (idx & 127)];
    }
    __syncthreads();
    float acc[8] = {};
    #pragma unroll 4
    for (int kk = 0; kk < 128; ++kk){
        float wv = Wx2[(size_t)(k0 + kk) * EXc + e];
        #pragma unroll
        for (int mm = 0; mm < 8; ++mm) acc[mm] += t1s[mm * 128 + kk] * wv;
    }
    #pragma unroll
    for (int mm = 0; mm < 8; ++mm)
        atomicAdd(&eXb[(size_t)(m0 + mm) * EXc + e], acc[mm]);
}

// ---------------- z2acc split-K: Z2Bacc += eXb @ Wb1[1:513] ----------------
__global__ __launch_bounds__(256) void z2acc_kernel(const float* __restrict__ eXb,
                                                    const float* __restrict__ Wb1,
                                                    float* __restrict__ Z2Bacc){
    __shared__ float exs[8 * 256];
    int b = blockIdx.x, tid = threadIdx.x;
    int mg = b & 31, hh = (b >> 5) & 7, kq = b >> 8;
    int m0 = mg * 8, h = hh * 256 + tid, k0 = kq * 256;
    #pragma unroll
    for (int l = 0; l < 8; ++l){
        int idx = tid + l * 256;
        exs[idx] = eXb[(size_t)(m0 + (idx >> 8)) * EXc + k0 + (idx & 255)];
    }
    __syncthreads();
    float acc[8] = {};
    #pragma unroll 4
    for (int kk = 0; kk < 256; ++kk){
        float wv = Wb1[(size_t)(1 + k0 + kk) * HBc + h];
        #pragma unroll
        for (int mm = 0; mm < 8; ++mm) acc[mm] += exs[mm * 256 + kk] * wv;
    }
    #pragma unroll
    for (int mm = 0; mm < 8; ++mm)
        atomicAdd(&Z2Bacc[(size_t)(m0 + mm) * HBc + h], acc[mm]);
}

// ---------------- tb: TB = tanh(Z2Bacc + (tk+tau_m)*Wb1[0] + cY) ----------------
__global__ void tb_kernel(const float* __restrict__ Z2Bacc, const float* __restrict__ Wb1,
                          const float* __restrict__ cY, const float* __restrict__ times_t,
                          const float* __restrict__ times_tau, const int* kptr,
                          float* __restrict__ TB){
    int b = blockIdx.x, tid = threadIdx.x;
    int m = b >> 3, h = (b & 7) * 256 + tid;
    float tk = times_t[kptr[0]];
    size_t idx = (size_t)m * HBc + h;
    float z = Z2Bacc[idx] + (tk + times_tau[m]) * Wb1[h] + cY[h];
    TB[idx] = fast_tanh(z);
}

// ---------------- act_delta: A1p = bf16(tanh(XW+SW[j]) - T1), packed A-layout, KTOT=32 ----------------
__global__ void act_delta_kernel(const float* __restrict__ XW, const float* __restrict__ T1,
                                 const float* __restrict__ SW, short* __restrict__ A1p){
    size_t grp = (size_t)blockIdx.x * 256 + threadIdx.x;  // 2,097,152 groups
    int lane = grp & 63;
    size_t t2 = grp >> 6;      // = mt*32 + kt
    int kt = t2 & 31;
    int mt = (int)(t2 >> 5);              // 0..1023
    int m  = mt * 16 + (lane & 15);       // global row 0..16383
    int c0 = kt * 32 + ((lane >> 4) << 3);
    int j    = m >> 8;
    int mloc = m & 255;
    const float* xwr = XW + (size_t)mloc * HXc + c0;
    const float* t1r = T1 + (size_t)mloc * HXc + c0;
    const float* swr = SW + (size_t)j * HXc + c0;
    short o8[8];
    #pragma unroll
    for (int i = 0; i < 8; ++i)
        o8[i] = f2bf(fast_tanh(xwr[i] + swr[i]) - t1r[i]);
    *(bf16x8*)(A1p + grp * 8) = *(bf16x8*)o8;
}

// ---- MFMA helpers ----
#define MMGRID(aa, bb) {                                                       \
    _Pragma("unroll") for (int i_ = 0; i_ < 4; ++i_)                           \
        _Pragma("unroll") for (int j_ = 0; j_ < 4; ++j_)                       \
            acc[i_][j_] = __builtin_amdgcn_mfma_f32_16x16x32_bf16(aa[i_], bb[j_], acc[i_][j_], 0, 0, 0); }

// stage BK=32 (1 kt): 8 A-chunks + 8 B-chunks of 1 KB; wave w stages 4 chunks
__device__ __forceinline__ void stage32(const short* __restrict__ Ap, const short* __restrict__ Bp,
                                        short* As, short* Bs,
                                        int at0, int bt0, int s, int KTOT, int wave, int lane){
    #pragma unroll
    for (int c = 0; c < 4; ++c){
        int ci = wave * 4 + c;            // 0..15
        int half = ci >> 3;               // 0 = A, 1 = B
        int t    = ci & 7;
        const short* src = half ? (Bp + ((size_t)(bt0 + t) * KTOT + s) * 512 + lane * 8)
                                : (Ap + ((size_t)(at0 + t) * KTOT + s) * 512 + lane * 8);
        short* dst = (half ? Bs : As) + t * 512;
        gld_lds16(src, dst);
    }
}

// compute one stage (1 kt x 16 MFMA per wave) from LDS
#define STAGE_COMPUTE(As, Bs) {                                                       \
    bf16x8 af[4], bfr[4];                                                             \
    _Pragma("unroll") for (int i_ = 0; i_ < 4; ++i_)                                  \
        af[i_] = *(const bf16x8*)((As) + ((wm * 4 + i_) * 512) + lane * 8);           \
    _Pragma("unroll") for (int j_ = 0; j_ < 4; ++j_)                                  \
        bfr[j_] = *(const bf16x8*)((Bs) + ((wn * 4 + j_) * 512) + lane * 8);          \
    MMGRID(af, bfr); }

// ---------------- w12: W12 = Wx2bf @ Wb1midbf (1024x2048, K=512), output in B-layout KTOT=32 ----------------
// grid (16, 8): bx = n-tile (h), by = m-tile (c). 128x128 tiles, S=16.
__global__ __launch_bounds__(256) void w12_mfma(
    const short* __restrict__ Ap, const short* __restrict__ Bp,
    short* __restrict__ W12p){
    const int KTOT = 16, S = 16;
    __shared__ __align__(16) short Asb[2][4096];
    __shared__ __align__(16) short Bsb[2][4096];
    int tid = threadIdx.x;
    int wave = tid >> 6, lane = tid & 63;
    int wm = wave >> 1, wn = wave & 1;
    int bx = blockIdx.x, by = blockIdx.y;
    int quad = lane >> 4, llo = lane & 15;
    f32x4 acc[4][4];
    #pragma unroll
    for (int i = 0; i < 4; ++i)
        #pragma unroll
        for (int j = 0; j < 4; ++j) acc[i][j] = (f32x4){0.f, 0.f, 0.f, 0.f};
    stage32(Ap, Bp, Asb[0], Bsb[0], by * 8, bx * 8, 0, KTOT, wave, lane);
    for (int s = 0; s < S; ++s){
        int buf = s & 1;
        __syncthreads();
        if (s + 1 < S)
            stage32(Ap, Bp, Asb[buf ^ 1], Bsb[buf ^ 1], by * 8, bx * 8, s + 1, KTOT, wave, lane);
        STAGE_COMPUTE(Asb[buf], Bsb[buf]);
    }
    // write W12[c][h] into B-fragment layout with KTOT2=32 (k=c, n=h)
    #pragma unroll
    for (int j = 0; j < 4; ++j){
        int h = bx * 128 + wn * 64 + j * 16 + llo;
        #pragma unroll
        for (int i = 0; i < 4; ++i){
            #pragma unroll
            for (int r = 0; r < 4; ++r){
                int c = by * 128 + wm * 64 + i * 16 + quad * 4 + r;
                W12p[(((size_t)(h >> 4) * 32 + (c >> 5)) * 64 + ((c & 31) >> 3) * 16 + llo) * 8 + (c & 7)] =
                    f2bf(acc[i][j][r]);
            }
        }
    }
}

// ---------------- gemm_big: Dz2 = A1p @ W12p, M=16384 N=2048 K=1024 (S=32); fused epilogue ----------------
// grid (bm=128, bn=16) -> XCD = bm%8 (A-slab locality).
__global__ __launch_bounds__(256) void gemm_big(
    const short* __restrict__ Ap, const short* __restrict__ Bp,
    const float* __restrict__ TB, const float* __restrict__ wrow,
    float* __restrict__ dacc){
    const int KTOT = 32, S = 32;
    __shared__ __align__(16) short Asb[2][4096];
    __shared__ __align__(16) short Bsb[2][4096];
    int tid = threadIdx.x;
    int wave = tid >> 6, lane = tid & 63;
    int wm = wave >> 1, wn = wave & 1;
    int bm = blockIdx.x, bn = blockIdx.y;
    int quad = lane >> 4, llo = lane & 15;
    f32x4 acc[4][4];
    #pragma unroll
    for (int i = 0; i < 4; ++i)
        #pragma unroll
        for (int j = 0; j < 4; ++j) acc[i][j] = (f32x4){0.f, 0.f, 0.f, 0.f};
    stage32(Ap, Bp, Asb[0], Bsb[0], bm * 8, bn * 8, 0, KTOT, wave, lane);
    for (int s = 0; s < S; ++s){
        int buf = s & 1;
        __syncthreads();
        if (s + 1 < S)
            stage32(Ap, Bp, Asb[buf ^ 1], Bsb[buf ^ 1], bm * 8, bn * 8, s + 1, KTOT, wave, lane);
        STAGE_COMPUTE(Asb[buf], Bsb[buf]);
    }
    // fused epilogue: tanh(zb+dz)-tanh(zb) = tdz*(1-tb^2)/(1+tb*tdz)
    int nj[4];
    #pragma unroll
    for (int j = 0; j < 4; ++j) nj[j] = bn * 128 + wn * 64 + j * 16 + llo;
    float part[4] = {0.f, 0.f, 0.f, 0.f};
    #pragma unroll
    for (int i = 0; i < 4; ++i){
        #pragma unroll
        for (int r = 0; r < 4; ++r){
            int m = bm * 128 + wm * 64 + i * 16 + quad * 4 + r;
            float wr = wrow[m];
            const float* trow = TB + (size_t)(m & 255) * HBc;
            #pragma unroll
            for (int j = 0; j < 4; ++j){
                float tb  = trow[nj[j]];
                float tdz = fast_tanh(acc[i][j][r]);
                float num = tdz * (1.0f - tb * tb);
                float den = 1.0f + tb * tdz;
                part[j] += wr * num * __builtin_amdgcn_rcpf(den);
            }
        }
    }
    #pragma unroll
    for (int j = 0; j < 4; ++j){
        part[j] += __shfl_xor(part[j], 16);
        part[j] += __shfl_xor(part[j], 32);
    }
    __shared__ float redn[128];
    if (tid < 128) redn[tid] = 0.f;
    __syncthreads();
    if (lane < 16){
        #pragma unroll
        for (int j = 0; j < 4; ++j)
            atomicAdd(&redn[wn * 64 + j * 16 + llo], part[j]);
    }
    __syncthreads();
    if (tid < 128) atomicAdd(&dacc[bn * 128 + tid], redn[tid]);
}

// ---------------- si = dacc @ Wb2, split over 8 blocks (out pre-zeroed in prep) ----------------
__global__ void out_kernel(const float* __restrict__ dacc, const float* __restrict__ Wb2,
                           float* __restrict__ out){
    __shared__ float red[4][64];
    int tid = threadIdx.x;
    int g = tid & 63, seg = tid >> 6;
    int h0 = blockIdx.x * 256 + seg * 64;
    float s = 0.f;
    #pragma unroll 8
    for (int hh = 0; hh < 64; ++hh)
        s += dacc[h0 + hh] * Wb2[(size_t)(h0 + hh) * GOUTc + g];
    red[seg][g] = s;
    __syncthreads();
    if (tid < 64)
        atomicAdd(&out[tid], red[0][tid] + red[1][tid] + red[2][tid] + red[3][tid]);
}

extern "C" void kernel_launch(void* const* d_in, const int* in_sizes, int n_in,
                              void* d_out, int out_size, void* d_ws, size_t ws_size,
                              hipStream_t stream){
    const float* X         = (const float*)d_in[0];
    const float* Y         = (const float*)d_in[1];
    const float* R         = (const float*)d_in[2];
    const float* stoich    = (const float*)d_in[3];
    const float* times_t   = (const float*)d_in[4];
    const float* times_tau = (const float*)d_in[5];
    const float* Wx1 = (const float*)d_in[6];
    const float* bx1 = (const float*)d_in[7];
    const float* Wx2 = (const float*)d_in[8];
    const float* bx2 = (const float*)d_in[9];
    const float* Wih = (const float*)d_in[10];
    const float* Whh = (const float*)d_in[11];
    const float* bh  = (const float*)d_in[12];
    const float* Wb1 = (const float*)d_in[13];
    const float* bb1 = (const float*)d_in[14];
    const float* Wb2 = (const float*)d_in[15];
    // d_in[16] = bb2: cancels in (nn_disp - nn), unused
    const int* kp  = (const int*)d_in[17];
    const int* kpp = (const int*)d_in[18];
    const int* qp  = (const int*)d_in[19];
    const int* qpp = (const int*)d_in[20];
    float* out = (float*)d_out;

    float* ws     = (float*)d_ws;
    float* hb0    = ws;                        // 512
    float* hb1    = ws + 512;                  // 512
    float* cY     = ws + 1024;                 // 2048
    float* dacc   = ws + 3072;                 // 2048
    float* wrow   = ws + 5120;                 // 64*256 = 16384
    float* SW     = ws + 21504;                // 64*1024 = 65536
    float* XW     = ws + 87040;                // 256*1024 = 262144
    float* T1     = ws + 349184;               // 256*1024 = 262144
    float* eXb    = ws + 611328;               // 256*512 = 131072
    float* TB     = ws + 742400;               // 256*2048 = 524288
    float* Z2Bacc = ws + 1266688;              // 256*2048 = 524288
    short* A1p    = (short*)(ws + 1790976);    // 16384*1024 bf16 = 8,388,608 float slots
    short* Wx2a   = (short*)(ws + 10179584);   // 1024*512 bf16 = 262,144 float slots
    short* Wb1p   = (short*)(ws + 10441728);   // 512*2048 bf16 = 524,288 float slots
    short* W12p   = (short*)(ws + 10966016);   // 1024*2048 bf16 = 1,048,576 float slots
    // total ws use: 12,014,592 floats = 48.1 MB

    prep_kernel     <<<4673, 256, 0, stream>>>(stoich, Wx1, Wx2, Wb1, X, R, bx1, bx2, kpp, qpp,
                                               SW, Wx2a, Wb1p, XW, T1, wrow, hb0, dacc, out,
                                               eXb, Z2Bacc);
    w12_mfma        <<<dim3(16, 8), 256, 0, stream>>>(Wx2a, Wb1p, W12p);
    act_delta_kernel<<<8192, 256, 0, stream>>>(XW, T1, SW, A1p);
    for (int s = 0; s < 8; ++s){
        const float* hc = (s & 1) ? hb1 : hb0;
        float*       hn = (s & 1) ? hb0 : hb1;
        rnn_step_kernel<<<8, 512, 0, stream>>>(Y, Wih, Whh, bh, kp, qp, hc, hn, s);
    }
    cy_kernel       <<<32,   256, 0, stream>>>(hb0, Wb1, bb1, cY);
    exbase_kernel   <<<512,  256, 0, stream>>>(T1, Wx2, eXb);
    z2acc_kernel    <<<512,  256, 0, stream>>>(eXb, Wb1, Z2Bacc);
    tb_kernel       <<<2048, 256, 0, stream>>>(Z2Bacc, Wb1, cY, times_t, times_tau, kp, TB);
    gemm_big        <<<dim3(128, 16), 256, 0, stream>>>(A1p, W12p, TB, wrow, dacc);
    out_kernel      <<<8,    256, 0, stream>>>(dacc, Wb2, out);
}

// Round 12
// 295.357 us; speedup vs baseline: 1.0413x; 1.0413x over previous
//
#include <hip/hip_runtime.h>
#include <math.h>

// Shapes (fixed by the reference)
#define DXc   16
#define MRc   64
#define MBARc 256
#define NTc   9
#define DYc   8
#define HXc   1024
#define EXc   512
#define HRc   512
#define HBc   2048
#define GOUTc 64
#define TOTc  2049   // (NT-1)*MBAR + 1

using bf16x8 = __attribute__((ext_vector_type(8))) short;
using f32x4  = __attribute__((ext_vector_type(4))) float;

typedef unsigned int u32;
typedef u32 __attribute__((address_space(1))) gbl_u32;
typedef u32 __attribute__((address_space(3))) lds_u32;

__device__ __forceinline__ float fast_tanh(float x){
    float e = __expf(2.0f * x);
    return 1.0f - 2.0f / (e + 1.0f);
}

// fp32 -> bf16 round-to-nearest-even (bit pattern in a short)
__device__ __forceinline__ short f2bf(float f){
    unsigned u = __builtin_bit_cast(unsigned, f);
    u = (u + 0x7FFFu + ((u >> 16) & 1u)) >> 16;
    return (short)u;
}

// async global->LDS: each lane loads 16 B from g + lane*16; LDS dest = base + lane*16
__device__ __forceinline__ void gld_lds16(const short* g, short* l){
    __builtin_amdgcn_global_load_lds((const gbl_u32*)g, (lds_u32*)l, 16, 0, 0);
}

// ---------------- prep: SW + packs (Wx2a A-layout, Wb1p B-layout) + XW/T1 + wrow + inits ----------------
// grid 4673 x 256
__global__ void prep_kernel(const float* __restrict__ stoich, const float* __restrict__ Wx1,
                            const float* __restrict__ Wx2, const float* __restrict__ Wb1,
                            const float* __restrict__ X, const float* __restrict__ R,
                            const float* __restrict__ bx1, const float* __restrict__ bx2,
                            const int* kpptr, const int* qpptr,
                            float* __restrict__ SW, short* __restrict__ Wx2a,
                            short* __restrict__ Wb1p, float* __restrict__ XW,
                            float* __restrict__ T1, float* __restrict__ wrow,
                            float* __restrict__ hb0, float* __restrict__ dacc,
                            float* __restrict__ outz, float* __restrict__ eXb,
                            float* __restrict__ Z2Bacc){
    int b = blockIdx.x, tid = threadIdx.x;
    if (b < 256){
        // SW[j][c] = stoich[:,j] @ Wx1
        int idx = b * 256 + tid;
        int j = idx >> 10, c = idx & 1023;
        float acc = 0.f;
        #pragma unroll
        for (int d = 0; d < DXc; ++d) acc += stoich[d * MRc + j] * Wx1[d * HXc + c];
        SW[idx] = acc;
    } else if (b < 512){
        // pack Wx2 (1024x512) into MFMA A-fragment order (M=c rows, K=e), KTOT=16
        size_t grp = (size_t)(b - 256) * 256 + tid;    // 65536 groups
        int lane = grp & 63;
        size_t t2 = grp >> 6;
        int kt = t2 & 15, mt = t2 >> 4;                // mt 0..63
        int c  = mt * 16 + (lane & 15);
        int e0 = kt * 32 + ((lane >> 4) << 3);
        short o8[8];
        #pragma unroll
        for (int jj = 0; jj < 8; ++jj) o8[jj] = f2bf(Wx2[(size_t)c * EXc + e0 + jj]);
        *(bf16x8*)(Wx2a + grp * 8) = *(bf16x8*)o8;
    } else if (b < 1024){
        // pack Wb1 rows 1..512 (512x2048) into B-fragment order, KTOT=16
        size_t grp = (size_t)(b - 512) * 256 + tid;
        int lane = grp & 63;
        size_t t2 = grp >> 6;
        int kt = t2 & 15, nt = t2 >> 4;
        int n  = nt * 16 + (lane & 15);
        int k0 = kt * 32 + ((lane >> 4) << 3);
        short o8[8];
        #pragma unroll
        for (int jj = 0; jj < 8; ++jj) o8[jj] = f2bf(Wb1[(size_t)(1 + k0 + jj) * HBc + n]);
        *(bf16x8*)(Wb1p + grp * 8) = *(bf16x8*)o8;
    } else if (b < 2048){
        // XW = Xbase@Wx1 + bx1 ; T1 = tanh(XW)
        int idx = (b - 1024) * 256 + tid;
        int m = idx >> 10, c = idx & 1023;
        int base = kpptr[0] * MBARc;
        const float* xr = X + ((size_t)qpptr[0] * TOTc + base + m) * DXc;
        float acc = bx1[c];
        #pragma unroll
        for (int d = 0; d < DXc; ++d) acc += xr[d] * Wx1[d * HXc + c];
        XW[idx] = acc;
        T1[idx] = fast_tanh(acc);
    } else if (b < 2112){
        // wrow[j*256+m] = valid(j,m) * R_delta
        int j = b - 2048, m = tid;
        int base = kpptr[0] * MBARc;
        int qp = qpptr[0];
        const float* xr = X + ((size_t)qp * TOTc + base + m) * DXc;
        bool valid = true;
        #pragma unroll
        for (int d = 0; d < DXc; ++d) valid = valid && (xr[d] + stoich[d * MRc + j] >= 0.f);
        size_t rb = (size_t)qp * TOTc * MRc;
        float rd = R[rb + (size_t)(base + 1 + m) * MRc + j] - R[rb + (size_t)(base + m) * MRc + j];
        wrow[j * MBARc + m] = valid ? rd : 0.f;
    } else if (b == 2112){
        hb0[tid] = 0.f; hb0[tid + 256] = 0.f;
        #pragma unroll
        for (int l = 0; l < 8; ++l) dacc[tid + l * 256] = 0.f;
        if (tid < GOUTc) outz[tid] = 0.f;
    } else if (b < 2625){
        // eXb init = bx2 (broadcast per row); 512 blocks, 131072 elems
        int idx = (b - 2113) * 256 + tid;
        eXb[idx] = bx2[idx & 511];
    } else {
        // Z2Bacc = 0; 2048 blocks, 524288 elems
        Z2Bacc[(size_t)(b - 2625) * 256 + tid] = 0.f;
    }
}

// ---------------- RNN step: h_next = tanh(y_t@Wih + h_cur@Whh + bh) ----------------
// 8 separate launches: stream-ordering provides the inter-step barrier (XCD-coherence safe).
__global__ __launch_bounds__(512) void rnn_step_kernel(
    const float* __restrict__ Y, const float* __restrict__ Wih,
    const float* __restrict__ Whh, const float* __restrict__ bh,
    const int* kptr, const int* qptr,
    const float* __restrict__ h_cur, float* __restrict__ h_next, int step){
    __shared__ float hs[HRc];
    __shared__ float psum[8][64];
    int tid = threadIdx.x;
    int o   = tid & 63;
    int seg = tid >> 6;
    int out = blockIdx.x * 64 + o;
    int k = kptr[0], q = qptr[0];
    int t = k + 1 + step;
    hs[tid] = h_cur[tid];
    __syncthreads();
    if (t >= NTc){
        if (seg == 0) h_next[out] = hs[out];
        return;
    }
    int k0 = seg * 64;
    float a0 = 0.f, a1 = 0.f, a2 = 0.f, a3 = 0.f;
    #pragma unroll 4
    for (int kk = 0; kk < 64; kk += 4){
        a0 += hs[k0 + kk + 0] * Whh[(size_t)(k0 + kk + 0) * HRc + out];
        a1 += hs[k0 + kk + 1] * Whh[(size_t)(k0 + kk + 1) * HRc + out];
        a2 += hs[k0 + kk + 2] * Whh[(size_t)(k0 + kk + 2) * HRc + out];
        a3 += hs[k0 + kk + 3] * Whh[(size_t)(k0 + kk + 3) * HRc + out];
    }
    psum[seg][o] = (a0 + a1) + (a2 + a3);
    __syncthreads();
    if (seg == 0){
        float a = 0.f;
        #pragma unroll
        for (int r = 0; r < 8; ++r) a += psum[r][o];
        const float* y = Y + (q * NTc + t) * DYc;
        float z = bh[out];
        #pragma unroll
        for (int d = 0; d < DYc; ++d) z += y[d] * Wih[d * HRc + out];
        h_next[out] = fast_tanh(z + a);
    }
}

// ---------------- cY[h] = bb1[h] + eY @ Wb1[513:1025], split-K in-block ----------------
__global__ __launch_bounds__(256) void cy_kernel(const float* __restrict__ eY,
                                                 const float* __restrict__ Wb1,
                                                 const float* __restrict__ bb1,
                                                 float* __restrict__ cY){
    __shared__ float psum[4][64];
    int tid = threadIdx.x;
    int o = tid & 63, seg = tid >> 6;
    int h = blockIdx.x * 64 + o;
    int e0 = seg * 128;
    float acc = 0.f;
    #pragma unroll 4
    for (int e = 0; e < 128; ++e)
        acc += eY[e0 + e] * Wb1[(size_t)(1 + EXc + e0 + e) * HBc + h];
    psum[seg][o] = acc;
    __syncthreads();
    if (seg == 0)
        cY[h] = bb1[h] + psum[0][o] + psum[1][o] + psum[2][o] + psum[3][o];
}

// ---------------- exbase split-K: eXb += T1 @ Wx2 (eXb pre-init to bx2) ----------------
__global__ __launch_bounds__(256) void exbase_kernel(const float* __restrict__ T1,
                                                     const float* __restrict__ Wx2,
                                                     float* __restrict__ eXb){
    __shared__ float t1s[8 * 128];
    int b = blockIdx.x, tid = threadIdx.x;
    int mg = b & 31, eh = (b >> 5) & 1, kq = b >> 6;
    int m0 = mg * 8, e = eh * 256 + tid, k0 = kq * 128;
    #pragma unroll
    for (int l = 0; l < 4; ++l){
        int idx = tid + l * 256;
        t1s[idx] = T1[(size_t)(m0 + (idx >> 7)) * HXc + k0 + (idx & 127)];
    }
    __syncthreads();
    float acc[8] = {};
    #pragma unroll 4
    for (int kk = 0; kk < 128; ++kk){
        float wv = Wx2[(size_t)(k0 + kk) * EXc + e];
        #pragma unroll
        for (int mm = 0; mm < 8; ++mm) acc[mm] += t1s[mm * 128 + kk] * wv;
    }
    #pragma unroll
    for (int mm = 0; mm < 8; ++mm)
        atomicAdd(&eXb[(size_t)(m0 + mm) * EXc + e], acc[mm]);
}

// ---------------- z2acc split-K: Z2Bacc += eXb @ Wb1[1:513] ----------------
__global__ __launch_bounds__(256) void z2acc_kernel(const float* __restrict__ eXb,
                                                    const float* __restrict__ Wb1,
                                                    float* __restrict__ Z2Bacc){
    __shared__ float exs[8 * 256];
    int b = blockIdx.x, tid = threadIdx.x;
    int mg = b & 31, hh = (b >> 5) & 7, kq = b >> 8;
    int m0 = mg * 8, h = hh * 256 + tid, k0 = kq * 256;
    #pragma unroll
    for (int l = 0; l < 8; ++l){
        int idx = tid + l * 256;
        exs[idx] = eXb[(size_t)(m0 + (idx >> 8)) * EXc + k0 + (idx & 255)];
    }
    __syncthreads();
    float acc[8] = {};
    #pragma unroll 4
    for (int kk = 0; kk < 256; ++kk){
        float wv = Wb1[(size_t)(1 + k0 + kk) * HBc + h];
        #pragma unroll
        for (int mm = 0; mm < 8; ++mm) acc[mm] += exs[mm * 256 + kk] * wv;
    }
    #pragma unroll
    for (int mm = 0; mm < 8; ++mm)
        atomicAdd(&Z2Bacc[(size_t)(m0 + mm) * HBc + h], acc[mm]);
}

// ---------------- tb: TB = tanh(Z2Bacc + (tk+tau_m)*Wb1[0] + cY) ----------------
__global__ void tb_kernel(const float* __restrict__ Z2Bacc, const float* __restrict__ Wb1,
                          const float* __restrict__ cY, const float* __restrict__ times_t,
                          const float* __restrict__ times_tau, const int* kptr,
                          float* __restrict__ TB){
    int b = blockIdx.x, tid = threadIdx.x;
    int m = b >> 3, h = (b & 7) * 256 + tid;
    float tk = times_t[kptr[0]];
    size_t idx = (size_t)m * HBc + h;
    float z = Z2Bacc[idx] + (tk + times_tau[m]) * Wb1[h] + cY[h];
    TB[idx] = fast_tanh(z);
}

// ---------------- act_delta: A1p = bf16(tanh(XW+SW[j]) - T1), packed A-layout, KTOT=32 ----------------
__global__ void act_delta_kernel(const float* __restrict__ XW, const float* __restrict__ T1,
                                 const float* __restrict__ SW, short* __restrict__ A1p){
    size_t grp = (size_t)blockIdx.x * 256 + threadIdx.x;  // 2,097,152 groups
    int lane = grp & 63;
    size_t t2 = grp >> 6;      // = mt*32 + kt
    int kt = t2 & 31;
    int mt = (int)(t2 >> 5);              // 0..1023
    int m  = mt * 16 + (lane & 15);       // global row 0..16383
    int c0 = kt * 32 + ((lane >> 4) << 3);
    int j    = m >> 8;
    int mloc = m & 255;
    const float* xwr = XW + (size_t)mloc * HXc + c0;
    const float* t1r = T1 + (size_t)mloc * HXc + c0;
    const float* swr = SW + (size_t)j * HXc + c0;
    short o8[8];
    #pragma unroll
    for (int i = 0; i < 8; ++i)
        o8[i] = f2bf(fast_tanh(xwr[i] + swr[i]) - t1r[i]);
    *(bf16x8*)(A1p + grp * 8) = *(bf16x8*)o8;
}

// ---- MFMA helpers (4x4 grid, used by w12) ----
#define MMGRID(aa, bb) {                                                       \
    _Pragma("unroll") for (int i_ = 0; i_ < 4; ++i_)                           \
        _Pragma("unroll") for (int j_ = 0; j_ < 4; ++j_)                       \
            acc[i_][j_] = __builtin_amdgcn_mfma_f32_16x16x32_bf16(aa[i_], bb[j_], acc[i_][j_], 0, 0, 0); }

// stage BK=32 (1 kt): 8 A-chunks + 8 B-chunks of 1 KB; wave w stages 4 chunks
__device__ __forceinline__ void stage32(const short* __restrict__ Ap, const short* __restrict__ Bp,
                                        short* As, short* Bs,
                                        int at0, int bt0, int s, int KTOT, int wave, int lane){
    #pragma unroll
    for (int c = 0; c < 4; ++c){
        int ci = wave * 4 + c;            // 0..15
        int half = ci >> 3;               // 0 = A, 1 = B
        int t    = ci & 7;
        const short* src = half ? (Bp + ((size_t)(bt0 + t) * KTOT + s) * 512 + lane * 8)
                                : (Ap + ((size_t)(at0 + t) * KTOT + s) * 512 + lane * 8);
        short* dst = (half ? Bs : As) + t * 512;
        gld_lds16(src, dst);
    }
}

// compute one stage (1 kt x 16 MFMA per wave) from LDS
#define STAGE_COMPUTE(As, Bs) {                                                       \
    bf16x8 af[4], bfr[4];                                                             \
    _Pragma("unroll") for (int i_ = 0; i_ < 4; ++i_)                                  \
        af[i_] = *(const bf16x8*)((As) + ((wm * 4 + i_) * 512) + lane * 8);           \
    _Pragma("unroll") for (int j_ = 0; j_ < 4; ++j_)                                  \
        bfr[j_] = *(const bf16x8*)((Bs) + ((wn * 4 + j_) * 512) + lane * 8);          \
    MMGRID(af, bfr); }

// ---------------- w12: W12 = Wx2bf @ Wb1midbf (1024x2048, K=512), output in B-layout KTOT=32 ----------------
// grid (16, 8): bx = n-tile (h), by = m-tile (c). 128x128 tiles, S=16.
__global__ __launch_bounds__(256) void w12_mfma(
    const short* __restrict__ Ap, const short* __restrict__ Bp,
    short* __restrict__ W12p){
    const int KTOT = 16, S = 16;
    __shared__ __align__(16) short Asb[2][4096];
    __shared__ __align__(16) short Bsb[2][4096];
    int tid = threadIdx.x;
    int wave = tid >> 6, lane = tid & 63;
    int wm = wave >> 1, wn = wave & 1;
    int bx = blockIdx.x, by = blockIdx.y;
    int quad = lane >> 4, llo = lane & 15;
    f32x4 acc[4][4];
    #pragma unroll
    for (int i = 0; i < 4; ++i)
        #pragma unroll
        for (int j = 0; j < 4; ++j) acc[i][j] = (f32x4){0.f, 0.f, 0.f, 0.f};
    stage32(Ap, Bp, Asb[0], Bsb[0], by * 8, bx * 8, 0, KTOT, wave, lane);
    for (int s = 0; s < S; ++s){
        int buf = s & 1;
        __syncthreads();
        if (s + 1 < S)
            stage32(Ap, Bp, Asb[buf ^ 1], Bsb[buf ^ 1], by * 8, bx * 8, s + 1, KTOT, wave, lane);
        STAGE_COMPUTE(Asb[buf], Bsb[buf]);
    }
    // write W12[c][h] into B-fragment layout with KTOT2=32 (k=c, n=h)
    #pragma unroll
    for (int j = 0; j < 4; ++j){
        int h = bx * 128 + wn * 64 + j * 16 + llo;
        #pragma unroll
        for (int i = 0; i < 4; ++i){
            #pragma unroll
            for (int r = 0; r < 4; ++r){
                int c = by * 128 + wm * 64 + i * 16 + quad * 4 + r;
                W12p[(((size_t)(h >> 4) * 32 + (c >> 5)) * 64 + ((c & 31) >> 3) * 16 + llo) * 8 + (c & 7)] =
                    f2bf(acc[i][j][r]);
            }
        }
    }
}

// ---- gemm_big: 4x8 microtile (wave 64x128, block 128x256) ----
// stage: 8 A-chunks + 16 B-chunks of 1 KB; wave w stages 6
__device__ __forceinline__ void stage24(const short* __restrict__ Ap, const short* __restrict__ Bp,
                                        short* As, short* Bs,
                                        int at0, int bt0, int s, int wave, int lane){
    #pragma unroll
    for (int c = 0; c < 6; ++c){
        int ci = wave * 6 + c;            // 0..23
        const short* src;
        short* dst;
        if (ci < 8){
            src = Ap + ((size_t)(at0 + ci) * 32 + s) * 512 + lane * 8;
            dst = As + ci * 512;
        } else {
            int t = ci - 8;
            src = Bp + ((size_t)(bt0 + t) * 32 + s) * 512 + lane * 8;
            dst = Bs + t * 512;
        }
        gld_lds16(src, dst);
    }
}

// ---------------- gemm_big: Dz2 = A1p @ W12p, M=16384 N=2048 K=1024 (S=32); fused epilogue ----------------
// grid (bm=128, bn=8) -> XCD = bm%8 (A-slab locality). Block tile 128x256, 4 waves 2x2, 4x8 frags.
__global__ __launch_bounds__(256, 2) void gemm_big(
    const short* __restrict__ Ap, const short* __restrict__ Bp,
    const float* __restrict__ TB, const float* __restrict__ wrow,
    float* __restrict__ dacc){
    const int S = 32;
    __shared__ __align__(16) short Asb[2][4096];    // 128 rows x 32 k
    __shared__ __align__(16) short Bsb[2][8192];    // 256 cols x 32 k
    int tid = threadIdx.x;
    int wave = tid >> 6, lane = tid & 63;
    int wm = wave >> 1, wn = wave & 1;
    int bm = blockIdx.x, bn = blockIdx.y;
    int quad = lane >> 4, llo = lane & 15;
    f32x4 acc[4][8];
    #pragma unroll
    for (int i = 0; i < 4; ++i)
        #pragma unroll
        for (int j = 0; j < 8; ++j) acc[i][j] = (f32x4){0.f, 0.f, 0.f, 0.f};
    stage24(Ap, Bp, Asb[0], Bsb[0], bm * 8, bn * 16, 0, wave, lane);
    for (int s = 0; s < S; ++s){
        int buf = s & 1;
        __syncthreads();
        if (s + 1 < S)
            stage24(Ap, Bp, Asb[buf ^ 1], Bsb[buf ^ 1], bm * 8, bn * 16, s + 1, wave, lane);
        {
            bf16x8 af[4], bfr[8];
            #pragma unroll
            for (int i = 0; i < 4; ++i)
                af[i] = *(const bf16x8*)(Asb[buf] + ((wm * 4 + i) * 512) + lane * 8);
            #pragma unroll
            for (int j = 0; j < 8; ++j)
                bfr[j] = *(const bf16x8*)(Bsb[buf] + ((wn * 8 + j) * 512) + lane * 8);
            #pragma unroll
            for (int i = 0; i < 4; ++i)
                #pragma unroll
                for (int j = 0; j < 8; ++j)
                    acc[i][j] = __builtin_amdgcn_mfma_f32_16x16x32_bf16(af[i], bfr[j], acc[i][j], 0, 0, 0);
        }
    }
    // fused epilogue: tanh(zb+dz)-tanh(zb) = tdz*(1-tb^2)/(1+tb*tdz)
    int nj[8];
    #pragma unroll
    for (int j = 0; j < 8; ++j) nj[j] = bn * 256 + wn * 128 + j * 16 + llo;
    float part[8] = {};
    #pragma unroll
    for (int i = 0; i < 4; ++i){
        #pragma unroll
        for (int r = 0; r < 4; ++r){
            int m = bm * 128 + wm * 64 + i * 16 + quad * 4 + r;
            float wr = wrow[m];
            const float* trow = TB + (size_t)(m & 255) * HBc;
            #pragma unroll
            for (int j = 0; j < 8; ++j){
                float tb  = trow[nj[j]];
                float tdz = fast_tanh(acc[i][j][r]);
                float num = tdz * (1.0f - tb * tb);
                float den = 1.0f + tb * tdz;
                part[j] += wr * num * __builtin_amdgcn_rcpf(den);
            }
        }
    }
    #pragma unroll
    for (int j = 0; j < 8; ++j){
        part[j] += __shfl_xor(part[j], 16);
        part[j] += __shfl_xor(part[j], 32);
    }
    __shared__ float redn[256];
    redn[tid] = 0.f;
    __syncthreads();
    if (lane < 16){
        #pragma unroll
        for (int j = 0; j < 8; ++j)
            atomicAdd(&redn[wn * 128 + j * 16 + llo], part[j]);
    }
    __syncthreads();
    atomicAdd(&dacc[bn * 256 + tid], redn[tid]);
}

// ---------------- si = dacc @ Wb2, split over 8 blocks (out pre-zeroed in prep) ----------------
__global__ void out_kernel(const float* __restrict__ dacc, const float* __restrict__ Wb2,
                           float* __restrict__ out){
    __shared__ float red[4][64];
    int tid = threadIdx.x;
    int g = tid & 63, seg = tid >> 6;
    int h0 = blockIdx.x * 256 + seg * 64;
    float s = 0.f;
    #pragma unroll 8
    for (int hh = 0; hh < 64; ++hh)
        s += dacc[h0 + hh] * Wb2[(size_t)(h0 + hh) * GOUTc + g];
    red[seg][g] = s;
    __syncthreads();
    if (tid < 64)
        atomicAdd(&out[tid], red[0][tid] + red[1][tid] + red[2][tid] + red[3][tid]);
}

extern "C" void kernel_launch(void* const* d_in, const int* in_sizes, int n_in,
                              void* d_out, int out_size, void* d_ws, size_t ws_size,
                              hipStream_t stream){
    const float* X         = (const float*)d_in[0];
    const float* Y         = (const float*)d_in[1];
    const float* R         = (const float*)d_in[2];
    const float* stoich    = (const float*)d_in[3];
    const float* times_t   = (const float*)d_in[4];
    const float* times_tau = (const float*)d_in[5];
    const float* Wx1 = (const float*)d_in[6];
    const float* bx1 = (const float*)d_in[7];
    const float* Wx2 = (const float*)d_in[8];
    const float* bx2 = (const float*)d_in[9];
    const float* Wih = (const float*)d_in[10];
    const float* Whh = (const float*)d_in[11];
    const float* bh  = (const float*)d_in[12];
    const float* Wb1 = (const float*)d_in[13];
    const float* bb1 = (const float*)d_in[14];
    const float* Wb2 = (const float*)d_in[15];
    // d_in[16] = bb2: cancels in (nn_disp - nn), unused
    const int* kp  = (const int*)d_in[17];
    const int* kpp = (const int*)d_in[18];
    const int* qp  = (const int*)d_in[19];
    const int* qpp = (const int*)d_in[20];
    float* out = (float*)d_out;

    float* ws     = (float*)d_ws;
    float* hb0    = ws;                        // 512
    float* hb1    = ws + 512;                  // 512
    float* cY     = ws + 1024;                 // 2048
    float* dacc   = ws + 3072;                 // 2048
    float* wrow   = ws + 5120;                 // 64*256 = 16384
    float* SW     = ws + 21504;                // 64*1024 = 65536
    float* XW     = ws + 87040;                // 256*1024 = 262144
    float* T1     = ws + 349184;               // 256*1024 = 262144
    float* eXb    = ws + 611328;               // 256*512 = 131072
    float* TB     = ws + 742400;               // 256*2048 = 524288
    float* Z2Bacc = ws + 1266688;              // 256*2048 = 524288
    short* A1p    = (short*)(ws + 1790976);    // 16384*1024 bf16 = 8,388,608 float slots
    short* Wx2a   = (short*)(ws + 10179584);   // 1024*512 bf16 = 262,144 float slots
    short* Wb1p   = (short*)(ws + 10441728);   // 512*2048 bf16 = 524,288 float slots
    short* W12p   = (short*)(ws + 10966016);   // 1024*2048 bf16 = 1,048,576 float slots
    // total ws use: ~12.0M floats = 48.1 MB

    prep_kernel     <<<4673, 256, 0, stream>>>(stoich, Wx1, Wx2, Wb1, X, R, bx1, bx2, kpp, qpp,
                                               SW, Wx2a, Wb1p, XW, T1, wrow, hb0, dacc, out,
                                               eXb, Z2Bacc);
    w12_mfma        <<<dim3(16, 8), 256, 0, stream>>>(Wx2a, Wb1p, W12p);
    act_delta_kernel<<<8192, 256, 0, stream>>>(XW, T1, SW, A1p);
    for (int s = 0; s < 8; ++s){
        const float* hc = (s & 1) ? hb1 : hb0;
        float*       hn = (s & 1) ? hb0 : hb1;
        rnn_step_kernel<<<8, 512, 0, stream>>>(Y, Wih, Whh, bh, kp, qp, hc, hn, s);
    }
    cy_kernel       <<<32,   256, 0, stream>>>(hb0, Wb1, bb1, cY);
    exbase_kernel   <<<512,  256, 0, stream>>>(T1, Wx2, eXb);
    z2acc_kernel    <<<512,  256, 0, stream>>>(eXb, Wb1, Z2Bacc);
    tb_kernel       <<<2048, 256, 0, stream>>>(Z2Bacc, Wb1, cY, times_t, times_tau, kp, TB);
    gemm_big        <<<dim3(128, 8), 256, 0, stream>>>(A1p, W12p, TB, wrow, dacc);
    out_kernel      <<<8,    256, 0, stream>>>(dacc, Wb2, out);
}

// Round 13
// 293.479 us; speedup vs baseline: 1.0480x; 1.0064x over previous
//
#include <hip/hip_runtime.h>
#include <math.h>

// Shapes (fixed by the reference)
#define DXc   16
#define MRc   64
#define MBARc 256
#define NTc   9
#define DYc   8
#define HXc   1024
#define EXc   512
#define HRc   512
#define HBc   2048
#define GOUTc 64
#define TOTc  2049   // (NT-1)*MBAR + 1

using bf16x8 = __attribute__((ext_vector_type(8))) short;
using f32x4  = __attribute__((ext_vector_type(4))) float;

typedef unsigned int u32;
typedef u32 __attribute__((address_space(1))) gbl_u32;
typedef u32 __attribute__((address_space(3))) lds_u32;

__device__ __forceinline__ float fast_tanh(float x){
    float e = __expf(2.0f * x);
    return 1.0f - 2.0f / (e + 1.0f);
}

// fp32 -> bf16 round-to-nearest-even (bit pattern in a short)
__device__ __forceinline__ short f2bf(float f){
    unsigned u = __builtin_bit_cast(unsigned, f);
    u = (u + 0x7FFFu + ((u >> 16) & 1u)) >> 16;
    return (short)u;
}

// async global->LDS: each lane loads 16 B from g + lane*16; LDS dest = base + lane*16
__device__ __forceinline__ void gld_lds16(const short* g, short* l){
    __builtin_amdgcn_global_load_lds((const gbl_u32*)g, (lds_u32*)l, 16, 0, 0);
}

// ---------------- prep: SW + packs (Wx2a A-layout, Wb1p B-layout) + XW/T1 + wrow + inits ----------------
// grid 4673 x 256
__global__ void prep_kernel(const float* __restrict__ stoich, const float* __restrict__ Wx1,
                            const float* __restrict__ Wx2, const float* __restrict__ Wb1,
                            const float* __restrict__ X, const float* __restrict__ R,
                            const float* __restrict__ bx1, const float* __restrict__ bx2,
                            const int* kpptr, const int* qpptr,
                            float* __restrict__ SW, short* __restrict__ Wx2a,
                            short* __restrict__ Wb1p, float* __restrict__ XW,
                            float* __restrict__ T1, float* __restrict__ wrow,
                            float* __restrict__ hb0, float* __restrict__ dacc,
                            float* __restrict__ outz, float* __restrict__ eXb,
                            float* __restrict__ Z2Bacc, int* __restrict__ cnt){
    int b = blockIdx.x, tid = threadIdx.x;
    if (b < 256){
        // SW[j][c] = stoich[:,j] @ Wx1
        int idx = b * 256 + tid;
        int j = idx >> 10, c = idx & 1023;
        float acc = 0.f;
        #pragma unroll
        for (int d = 0; d < DXc; ++d) acc += stoich[d * MRc + j] * Wx1[d * HXc + c];
        SW[idx] = acc;
    } else if (b < 512){
        // pack Wx2 (1024x512) into MFMA A-fragment order (M=c rows, K=e), KTOT=16
        size_t grp = (size_t)(b - 256) * 256 + tid;    // 65536 groups
        int lane = grp & 63;
        size_t t2 = grp >> 6;
        int kt = t2 & 15, mt = t2 >> 4;                // mt 0..63
        int c  = mt * 16 + (lane & 15);
        int e0 = kt * 32 + ((lane >> 4) << 3);
        short o8[8];
        #pragma unroll
        for (int jj = 0; jj < 8; ++jj) o8[jj] = f2bf(Wx2[(size_t)c * EXc + e0 + jj]);
        *(bf16x8*)(Wx2a + grp * 8) = *(bf16x8*)o8;
    } else if (b < 1024){
        // pack Wb1 rows 1..512 (512x2048) into B-fragment order, KTOT=16
        size_t grp = (size_t)(b - 512) * 256 + tid;
        int lane = grp & 63;
        size_t t2 = grp >> 6;
        int kt = t2 & 15, nt = t2 >> 4;
        int n  = nt * 16 + (lane & 15);
        int k0 = kt * 32 + ((lane >> 4) << 3);
        short o8[8];
        #pragma unroll
        for (int jj = 0; jj < 8; ++jj) o8[jj] = f2bf(Wb1[(size_t)(1 + k0 + jj) * HBc + n]);
        *(bf16x8*)(Wb1p + grp * 8) = *(bf16x8*)o8;
    } else if (b < 2048){
        // XW = Xbase@Wx1 + bx1 ; T1 = tanh(XW)
        int idx = (b - 1024) * 256 + tid;
        int m = idx >> 10, c = idx & 1023;
        int base = kpptr[0] * MBARc;
        const float* xr = X + ((size_t)qpptr[0] * TOTc + base + m) * DXc;
        float acc = bx1[c];
        #pragma unroll
        for (int d = 0; d < DXc; ++d) acc += xr[d] * Wx1[d * HXc + c];
        XW[idx] = acc;
        T1[idx] = fast_tanh(acc);
    } else if (b < 2112){
        // wrow[j*256+m] = valid(j,m) * R_delta
        int j = b - 2048, m = tid;
        int base = kpptr[0] * MBARc;
        int qp = qpptr[0];
        const float* xr = X + ((size_t)qp * TOTc + base + m) * DXc;
        bool valid = true;
        #pragma unroll
        for (int d = 0; d < DXc; ++d) valid = valid && (xr[d] + stoich[d * MRc + j] >= 0.f);
        size_t rb = (size_t)qp * TOTc * MRc;
        float rd = R[rb + (size_t)(base + 1 + m) * MRc + j] - R[rb + (size_t)(base + m) * MRc + j];
        wrow[j * MBARc + m] = valid ? rd : 0.f;
    } else if (b == 2112){
        hb0[tid] = 0.f; hb0[tid + 256] = 0.f;
        #pragma unroll
        for (int l = 0; l < 8; ++l) dacc[tid + l * 256] = 0.f;
        if (tid < GOUTc) outz[tid] = 0.f;
        if (tid == 0) cnt[0] = 0;
    } else if (b < 2625){
        // eXb init = bx2 (broadcast per row); 512 blocks, 131072 elems
        int idx = (b - 2113) * 256 + tid;
        eXb[idx] = bx2[idx & 511];
    } else {
        // Z2Bacc = 0; 2048 blocks, 524288 elems
        Z2Bacc[(size_t)(b - 2625) * 256 + tid] = 0.f;
    }
}

// ---- MFMA helpers (4x4 grid, used by w12) ----
#define MMGRID(aa, bb) {                                                       \
    _Pragma("unroll") for (int i_ = 0; i_ < 4; ++i_)                           \
        _Pragma("unroll") for (int j_ = 0; j_ < 4; ++j_)                       \
            acc[i_][j_] = __builtin_amdgcn_mfma_f32_16x16x32_bf16(aa[i_], bb[j_], acc[i_][j_], 0, 0, 0); }

// stage BK=32 (1 kt): 8 A-chunks + 8 B-chunks of 1 KB; wave w stages 4 chunks
__device__ __forceinline__ void stage32(const short* __restrict__ Ap, const short* __restrict__ Bp,
                                        short* As, short* Bs,
                                        int at0, int bt0, int s, int KTOT, int wave, int lane){
    #pragma unroll
    for (int c = 0; c < 4; ++c){
        int ci = wave * 4 + c;            // 0..15
        int half = ci >> 3;               // 0 = A, 1 = B
        int t    = ci & 7;
        const short* src = half ? (Bp + ((size_t)(bt0 + t) * KTOT + s) * 512 + lane * 8)
                                : (Ap + ((size_t)(at0 + t) * KTOT + s) * 512 + lane * 8);
        short* dst = (half ? Bs : As) + t * 512;
        gld_lds16(src, dst);
    }
}

// compute one stage (1 kt x 16 MFMA per wave) from LDS
#define STAGE_COMPUTE(As, Bs) {                                                       \
    bf16x8 af[4], bfr[4];                                                             \
    _Pragma("unroll") for (int i_ = 0; i_ < 4; ++i_)                                  \
        af[i_] = *(const bf16x8*)((As) + ((wm * 4 + i_) * 512) + lane * 8);           \
    _Pragma("unroll") for (int j_ = 0; j_ < 4; ++j_)                                  \
        bfr[j_] = *(const bf16x8*)((Bs) + ((wn * 4 + j_) * 512) + lane * 8);          \
    MMGRID(af, bfr); }

// ---------------- fused w12 + act_delta + exbase (independent works, one dispatch) ----------------
// blocks [0,128): w12 = Wx2bf @ Wb1midbf -> W12p (B-layout KTOT=32)
// blocks [128,8320): act_delta -> A1p
// blocks [8320,8832): exbase split-K -> eXb (+= T1 @ Wx2)
__global__ __launch_bounds__(256) void w12_act_ex_kernel(
    const short* __restrict__ Wx2a, const short* __restrict__ Wb1p,
    short* __restrict__ W12p,
    const float* __restrict__ XW, const float* __restrict__ T1,
    const float* __restrict__ SW, short* __restrict__ A1p,
    const float* __restrict__ Wx2, float* __restrict__ eXb){
    __shared__ __align__(16) short Asb[2][4096];
    __shared__ __align__(16) short Bsb[2][4096];
    int b = blockIdx.x, tid = threadIdx.x;
    if (b < 128){
        // ---- w12: 128x128 tiles, K=512 (S=16) ----
        const int KTOT = 16, S = 16;
        int wave = tid >> 6, lane = tid & 63;
        int wm = wave >> 1, wn = wave & 1;
        int bx = b & 15, by = b >> 4;
        int quad = lane >> 4, llo = lane & 15;
        f32x4 acc[4][4];
        #pragma unroll
        for (int i = 0; i < 4; ++i)
            #pragma unroll
            for (int j = 0; j < 4; ++j) acc[i][j] = (f32x4){0.f, 0.f, 0.f, 0.f};
        stage32(Wx2a, Wb1p, Asb[0], Bsb[0], by * 8, bx * 8, 0, KTOT, wave, lane);
        for (int s = 0; s < S; ++s){
            int buf = s & 1;
            __syncthreads();
            if (s + 1 < S)
                stage32(Wx2a, Wb1p, Asb[buf ^ 1], Bsb[buf ^ 1], by * 8, bx * 8, s + 1, KTOT, wave, lane);
            STAGE_COMPUTE(Asb[buf], Bsb[buf]);
        }
        // write W12[c][h] into B-fragment layout with KTOT2=32 (k=c, n=h)
        #pragma unroll
        for (int j = 0; j < 4; ++j){
            int h = bx * 128 + wn * 64 + j * 16 + llo;
            #pragma unroll
            for (int i = 0; i < 4; ++i){
                #pragma unroll
                for (int r = 0; r < 4; ++r){
                    int c = by * 128 + wm * 64 + i * 16 + quad * 4 + r;
                    W12p[(((size_t)(h >> 4) * 32 + (c >> 5)) * 64 + ((c & 31) >> 3) * 16 + llo) * 8 + (c & 7)] =
                        f2bf(acc[i][j][r]);
                }
            }
        }
    } else if (b < 8320){
        // ---- act_delta: A1p = bf16(tanh(XW+SW[j]) - T1), packed A-layout, KTOT=32 ----
        size_t grp = (size_t)(b - 128) * 256 + tid;  // 2,097,152 groups
        int lane = grp & 63;
        size_t t2 = grp >> 6;      // = mt*32 + kt
        int kt = t2 & 31;
        int mt = (int)(t2 >> 5);              // 0..1023
        int m  = mt * 16 + (lane & 15);       // global row 0..16383
        int c0 = kt * 32 + ((lane >> 4) << 3);
        int j    = m >> 8;
        int mloc = m & 255;
        const float* xwr = XW + (size_t)mloc * HXc + c0;
        const float* t1r = T1 + (size_t)mloc * HXc + c0;
        const float* swr = SW + (size_t)j * HXc + c0;
        short o8[8];
        #pragma unroll
        for (int i = 0; i < 8; ++i)
            o8[i] = f2bf(fast_tanh(xwr[i] + swr[i]) - t1r[i]);
        *(bf16x8*)(A1p + grp * 8) = *(bf16x8*)o8;
    } else {
        // ---- exbase split-K: eXb += T1 @ Wx2 (eXb pre-init to bx2) ----
        __shared__ float t1s[8 * 128];
        int bb = b - 8320;                   // 0..511
        int mg = bb & 31, eh = (bb >> 5) & 1, kq = bb >> 6;
        int m0 = mg * 8, e = eh * 256 + tid, k0 = kq * 128;
        #pragma unroll
        for (int l = 0; l < 4; ++l){
            int idx = tid + l * 256;
            t1s[idx] = T1[(size_t)(m0 + (idx >> 7)) * HXc + k0 + (idx & 127)];
        }
        __syncthreads();
        float acc[8] = {};
        #pragma unroll 4
        for (int kk = 0; kk < 128; ++kk){
            float wv = Wx2[(size_t)(k0 + kk) * EXc + e];
            #pragma unroll
            for (int mm = 0; mm < 8; ++mm) acc[mm] += t1s[mm * 128 + kk] * wv;
        }
        #pragma unroll
        for (int mm = 0; mm < 8; ++mm)
            atomicAdd(&eXb[(size_t)(m0 + mm) * EXc + e], acc[mm]);
    }
}

// ---------------- RNN (8 steps) + cY, one kernel, grid 8 x 512 ----------------
// Cross-block data passes ONLY through agent-scope atomic store/load (XCD-coherent);
// counter-gated so all step-s stores complete before any step-s+1 load issues.
__global__ __launch_bounds__(512) void rnn_cy_kernel(
    const float* __restrict__ Y, const float* __restrict__ Wih,
    const float* __restrict__ Whh, const float* __restrict__ bh,
    const float* __restrict__ Wb1, const float* __restrict__ bb1,
    const int* kptr, const int* qptr,
    float* __restrict__ hb0, float* __restrict__ hb1,
    int* __restrict__ cnt, float* __restrict__ cY){
    __shared__ float hs[HRc];
    __shared__ float psum[8][64];
    __shared__ float ps2[2][256];
    int tid = threadIdx.x;
    int o = tid & 63, seg = tid >> 6;
    int b = blockIdx.x;
    int out = b * 64 + o;
    int k = kptr[0], q = qptr[0];
    hs[tid] = 0.f;
    __syncthreads();
    for (int s = 0; s < 8; ++s){
        float* dst = (s & 1) ? hb0 : hb1;
        if (s > 0){
            const float* src = (s & 1) ? hb1 : hb0;
            if (tid == 0){
                int guard = 0;
                while (__hip_atomic_load(cnt, __ATOMIC_ACQUIRE, __HIP_MEMORY_SCOPE_AGENT) < 8 * s
                       && ++guard < (1 << 26)) {}
            }
            __syncthreads();
            hs[tid] = __hip_atomic_load(src + tid, __ATOMIC_RELAXED, __HIP_MEMORY_SCOPE_AGENT);
            __syncthreads();
        }
        int t = k + 1 + s;
        if (t < NTc){
            int k0 = seg * 64;
            float a0 = 0.f, a1 = 0.f, a2 = 0.f, a3 = 0.f;
            #pragma unroll 4
            for (int kk = 0; kk < 64; kk += 4){
                a0 += hs[k0 + kk + 0] * Whh[(size_t)(k0 + kk + 0) * HRc + out];
                a1 += hs[k0 + kk + 1] * Whh[(size_t)(k0 + kk + 1) * HRc + out];
                a2 += hs[k0 + kk + 2] * Whh[(size_t)(k0 + kk + 2) * HRc + out];
                a3 += hs[k0 + kk + 3] * Whh[(size_t)(k0 + kk + 3) * HRc + out];
            }
            psum[seg][o] = (a0 + a1) + (a2 + a3);
            __syncthreads();
            if (seg == 0){
                float a = 0.f;
                #pragma unroll
                for (int r = 0; r < 8; ++r) a += psum[r][o];
                const float* y = Y + (q * NTc + t) * DYc;
                float z = bh[out];
                #pragma unroll
                for (int d = 0; d < DYc; ++d) z += y[d] * Wih[d * HRc + out];
                __hip_atomic_store(dst + out, fast_tanh(z + a), __ATOMIC_RELEASE, __HIP_MEMORY_SCOPE_AGENT);
            }
            __syncthreads();
        } else {
            if (seg == 0)
                __hip_atomic_store(dst + out, hs[out], __ATOMIC_RELEASE, __HIP_MEMORY_SCOPE_AGENT);
            __syncthreads();
        }
        if (tid == 0)
            __hip_atomic_fetch_add(cnt, 1, __ATOMIC_RELEASE, __HIP_MEMORY_SCOPE_AGENT);
    }
    // ---- cY phase: final eY is in hb0 ----
    if (tid == 0){
        int guard = 0;
        while (__hip_atomic_load(cnt, __ATOMIC_ACQUIRE, __HIP_MEMORY_SCOPE_AGENT) < 64
               && ++guard < (1 << 26)) {}
    }
    __syncthreads();
    hs[tid] = __hip_atomic_load(hb0 + tid, __ATOMIC_RELAXED, __HIP_MEMORY_SCOPE_AGENT);
    __syncthreads();
    int o2 = tid & 255, sg = tid >> 8;
    int h = b * 256 + o2;
    float acc = 0.f;
    int e0 = sg * 256;
    #pragma unroll 4
    for (int e = 0; e < 256; ++e)
        acc += hs[e0 + e] * Wb1[(size_t)(1 + EXc + e0 + e) * HBc + h];
    ps2[sg][o2] = acc;
    __syncthreads();
    if (sg == 0)
        cY[h] = bb1[h] + ps2[0][o2] + ps2[1][o2];
}

// ---------------- z2acc split-K: Z2Bacc += eXb @ Wb1[1:513] ----------------
__global__ __launch_bounds__(256) void z2acc_kernel(const float* __restrict__ eXb,
                                                    const float* __restrict__ Wb1,
                                                    float* __restrict__ Z2Bacc){
    __shared__ float exs[8 * 256];
    int b = blockIdx.x, tid = threadIdx.x;
    int mg = b & 31, hh = (b >> 5) & 7, kq = b >> 8;
    int m0 = mg * 8, h = hh * 256 + tid, k0 = kq * 256;
    #pragma unroll
    for (int l = 0; l < 8; ++l){
        int idx = tid + l * 256;
        exs[idx] = eXb[(size_t)(m0 + (idx >> 8)) * EXc + k0 + (idx & 255)];
    }
    __syncthreads();
    float acc[8] = {};
    #pragma unroll 4
    for (int kk = 0; kk < 256; ++kk){
        float wv = Wb1[(size_t)(1 + k0 + kk) * HBc + h];
        #pragma unroll
        for (int mm = 0; mm < 8; ++mm) acc[mm] += exs[mm * 256 + kk] * wv;
    }
    #pragma unroll
    for (int mm = 0; mm < 8; ++mm)
        atomicAdd(&Z2Bacc[(size_t)(m0 + mm) * HBc + h], acc[mm]);
}

// ---------------- tb: TB = tanh(Z2Bacc + (tk+tau_m)*Wb1[0] + cY) ----------------
__global__ void tb_kernel(const float* __restrict__ Z2Bacc, const float* __restrict__ Wb1,
                          const float* __restrict__ cY, const float* __restrict__ times_t,
                          const float* __restrict__ times_tau, const int* kptr,
                          float* __restrict__ TB){
    int b = blockIdx.x, tid = threadIdx.x;
    int m = b >> 3, h = (b & 7) * 256 + tid;
    float tk = times_t[kptr[0]];
    size_t idx = (size_t)m * HBc + h;
    float z = Z2Bacc[idx] + (tk + times_tau[m]) * Wb1[h] + cY[h];
    TB[idx] = fast_tanh(z);
}

// ---- gemm_big: 4x8 microtile (wave 64x128, block 128x256) ----
// stage: 8 A-chunks + 16 B-chunks of 1 KB; wave w stages 6
__device__ __forceinline__ void stage24(const short* __restrict__ Ap, const short* __restrict__ Bp,
                                        short* As, short* Bs,
                                        int at0, int bt0, int s, int wave, int lane){
    #pragma unroll
    for (int c = 0; c < 6; ++c){
        int ci = wave * 6 + c;            // 0..23
        const short* src;
        short* dst;
        if (ci < 8){
            src = Ap + ((size_t)(at0 + ci) * 32 + s) * 512 + lane * 8;
            dst = As + ci * 512;
        } else {
            int t = ci - 8;
            src = Bp + ((size_t)(bt0 + t) * 32 + s) * 512 + lane * 8;
            dst = Bs + t * 512;
        }
        gld_lds16(src, dst);
    }
}

// ---------------- gemm_big: Dz2 = A1p @ W12p, M=16384 N=2048 K=1024 (S=32); fused epilogue ----------------
// grid (bm=128, bn=8) -> XCD = bm%8 (A-slab locality). Block tile 128x256, 4 waves 2x2, 4x8 frags.
__global__ __launch_bounds__(256, 2) void gemm_big(
    const short* __restrict__ Ap, const short* __restrict__ Bp,
    const float* __restrict__ TB, const float* __restrict__ wrow,
    float* __restrict__ dacc){
    const int S = 32;
    __shared__ __align__(16) short Asb[2][4096];    // 128 rows x 32 k
    __shared__ __align__(16) short Bsb[2][8192];    // 256 cols x 32 k
    int tid = threadIdx.x;
    int wave = tid >> 6, lane = tid & 63;
    int wm = wave >> 1, wn = wave & 1;
    int bm = blockIdx.x, bn = blockIdx.y;
    int quad = lane >> 4, llo = lane & 15;
    f32x4 acc[4][8];
    #pragma unroll
    for (int i = 0; i < 4; ++i)
        #pragma unroll
        for (int j = 0; j < 8; ++j) acc[i][j] = (f32x4){0.f, 0.f, 0.f, 0.f};
    stage24(Ap, Bp, Asb[0], Bsb[0], bm * 8, bn * 16, 0, wave, lane);
    for (int s = 0; s < S; ++s){
        int buf = s & 1;
        __syncthreads();
        if (s + 1 < S)
            stage24(Ap, Bp, Asb[buf ^ 1], Bsb[buf ^ 1], bm * 8, bn * 16, s + 1, wave, lane);
        {
            bf16x8 af[4], bfr[8];
            #pragma unroll
            for (int i = 0; i < 4; ++i)
                af[i] = *(const bf16x8*)(Asb[buf] + ((wm * 4 + i) * 512) + lane * 8);
            #pragma unroll
            for (int j = 0; j < 8; ++j)
                bfr[j] = *(const bf16x8*)(Bsb[buf] + ((wn * 8 + j) * 512) + lane * 8);
            #pragma unroll
            for (int i = 0; i < 4; ++i)
                #pragma unroll
                for (int j = 0; j < 8; ++j)
                    acc[i][j] = __builtin_amdgcn_mfma_f32_16x16x32_bf16(af[i], bfr[j], acc[i][j], 0, 0, 0);
        }
    }
    // fused epilogue: tanh(zb+dz)-tanh(zb) = tdz*(1-tb^2)/(1+tb*tdz)
    int nj[8];
    #pragma unroll
    for (int j = 0; j < 8; ++j) nj[j] = bn * 256 + wn * 128 + j * 16 + llo;
    float part[8] = {};
    #pragma unroll
    for (int i = 0; i < 4; ++i){
        #pragma unroll
        for (int r = 0; r < 4; ++r){
            int m = bm * 128 + wm * 64 + i * 16 + quad * 4 + r;
            float wr = wrow[m];
            const float* trow = TB + (size_t)(m & 255) * HBc;
            #pragma unroll
            for (int j = 0; j < 8; ++j){
                float tb  = trow[nj[j]];
                float tdz = fast_tanh(acc[i][j][r]);
                float num = tdz * (1.0f - tb * tb);
                float den = 1.0f + tb * tdz;
                part[j] += wr * num * __builtin_amdgcn_rcpf(den);
            }
        }
    }
    #pragma unroll
    for (int j = 0; j < 8; ++j){
        part[j] += __shfl_xor(part[j], 16);
        part[j] += __shfl_xor(part[j], 32);
    }
    __shared__ float redn[256];
    redn[tid] = 0.f;
    __syncthreads();
    if (lane < 16){
        #pragma unroll
        for (int j = 0; j < 8; ++j)
            atomicAdd(&redn[wn * 128 + j * 16 + llo], part[j]);
    }
    __syncthreads();
    atomicAdd(&dacc[bn * 256 + tid], redn[tid]);
}

// ---------------- si = dacc @ Wb2, split over 8 blocks (out pre-zeroed in prep) ----------------
__global__ void out_kernel(const float* __restrict__ dacc, const float* __restrict__ Wb2,
                           float* __restrict__ out){
    __shared__ float red[4][64];
    int tid = threadIdx.x;
    int g = tid & 63, seg = tid >> 6;
    int h0 = blockIdx.x * 256 + seg * 64;
    float s = 0.f;
    #pragma unroll 8
    for (int hh = 0; hh < 64; ++hh)
        s += dacc[h0 + hh] * Wb2[(size_t)(h0 + hh) * GOUTc + g];
    red[seg][g] = s;
    __syncthreads();
    if (tid < 64)
        atomicAdd(&out[tid], red[0][tid] + red[1][tid] + red[2][tid] + red[3][tid]);
}

extern "C" void kernel_launch(void* const* d_in, const int* in_sizes, int n_in,
                              void* d_out, int out_size, void* d_ws, size_t ws_size,
                              hipStream_t stream){
    const float* X         = (const float*)d_in[0];
    const float* Y         = (const float*)d_in[1];
    const float* R         = (const float*)d_in[2];
    const float* stoich    = (const float*)d_in[3];
    const float* times_t   = (const float*)d_in[4];
    const float* times_tau = (const float*)d_in[5];
    const float* Wx1 = (const float*)d_in[6];
    const float* bx1 = (const float*)d_in[7];
    const float* Wx2 = (const float*)d_in[8];
    const float* bx2 = (const float*)d_in[9];
    const float* Wih = (const float*)d_in[10];
    const float* Whh = (const float*)d_in[11];
    const float* bh  = (const float*)d_in[12];
    const float* Wb1 = (const float*)d_in[13];
    const float* bb1 = (const float*)d_in[14];
    const float* Wb2 = (const float*)d_in[15];
    // d_in[16] = bb2: cancels in (nn_disp - nn), unused
    const int* kp  = (const int*)d_in[17];
    const int* kpp = (const int*)d_in[18];
    const int* qp  = (const int*)d_in[19];
    const int* qpp = (const int*)d_in[20];
    float* out = (float*)d_out;

    float* ws     = (float*)d_ws;
    float* hb0    = ws;                        // 512
    float* hb1    = ws + 512;                  // 512
    float* cY     = ws + 1024;                 // 2048
    float* dacc   = ws + 3072;                 // 2048
    float* wrow   = ws + 5120;                 // 64*256 = 16384
    float* SW     = ws + 21504;                // 64*1024 = 65536
    float* XW     = ws + 87040;                // 256*1024 = 262144
    float* T1     = ws + 349184;               // 256*1024 = 262144
    float* eXb    = ws + 611328;               // 256*512 = 131072
    float* TB     = ws + 742400;               // 256*2048 = 524288
    float* Z2Bacc = ws + 1266688;              // 256*2048 = 524288
    short* A1p    = (short*)(ws + 1790976);    // 16384*1024 bf16 = 8,388,608 float slots
    short* Wx2a   = (short*)(ws + 10179584);   // 1024*512 bf16 = 262,144 float slots
    short* Wb1p   = (short*)(ws + 10441728);   // 512*2048 bf16 = 524,288 float slots
    short* W12p   = (short*)(ws + 10966016);   // 1024*2048 bf16 = 1,048,576 float slots
    int*   cnt    = (int*)(ws + 12014592);     // 1 int (RNN step counter)
    // total ws use: ~12.0M floats = 48.1 MB

    prep_kernel      <<<4673, 256, 0, stream>>>(stoich, Wx1, Wx2, Wb1, X, R, bx1, bx2, kpp, qpp,
                                                SW, Wx2a, Wb1p, XW, T1, wrow, hb0, dacc, out,
                                                eXb, Z2Bacc, cnt);
    w12_act_ex_kernel<<<8832, 256, 0, stream>>>(Wx2a, Wb1p, W12p, XW, T1, SW, A1p, Wx2, eXb);
    rnn_cy_kernel    <<<8,    512, 0, stream>>>(Y, Wih, Whh, bh, Wb1, bb1, kp, qp, hb0, hb1, cnt, cY);
    z2acc_kernel     <<<512,  256, 0, stream>>>(eXb, Wb1, Z2Bacc);
    tb_kernel        <<<2048, 256, 0, stream>>>(Z2Bacc, Wb1, cY, times_t, times_tau, kp, TB);
    gemm_big         <<<dim3(128, 8), 256, 0, stream>>>(A1p, W12p, TB, wrow, dacc);
    out_kernel       <<<8,    256, 0, stream>>>(dacc, Wb2, out);
}